// Round 1
// baseline (510.534 us; speedup 1.0000x reference)
//
#include <hip/hip_runtime.h>

#define BS 64
#define CI 64
#define LEN 4096
#define CO 128
#define KS 7
#define NK 4
#define HID 16
#define TEMP 30.0f

#define OTILE 32       // outputs per block
#define LHALF 2048     // L per block
#define LCHUNK 256     // L per chunk iteration
#define LT 8           // l per thread

// ws layout (floats): pooled[BS*CI] @0, att[BS*NK] @4096, aggb[BS*CO] @4352

__global__ void pool_kernel(const float* __restrict__ x, float* __restrict__ pooled) {
    int bc = blockIdx.x;                 // b*CI + i
    const float* xp = x + (size_t)bc * LEN;
    int t = threadIdx.x;
    float s = 0.f;
#pragma unroll
    for (int j = 0; j < LEN / 256; ++j) s += xp[t + 256 * j];
#pragma unroll
    for (int off = 32; off > 0; off >>= 1) s += __shfl_down(s, off, 64);
    __shared__ float red[4];
    if ((t & 63) == 0) red[t >> 6] = s;
    __syncthreads();
    if (t == 0) pooled[bc] = (red[0] + red[1] + red[2] + red[3]) * (1.0f / LEN);
}

__global__ void attn_kernel(const float* __restrict__ pooled,
                            const float* __restrict__ w1,
                            const float* __restrict__ w2,
                            const float* __restrict__ bias,
                            float* __restrict__ att_g,
                            float* __restrict__ aggb_g) {
    int b = blockIdx.x, t = threadIdx.x;
    __shared__ float p[CI], h[HID], att[NK];
    if (t < CI) p[t] = pooled[b * CI + t];
    __syncthreads();
    if (t < HID) {
        float s = 0.f;
        for (int i = 0; i < CI; ++i) s += p[i] * w1[t * CI + i];
        h[t] = fmaxf(s, 0.f);
    }
    __syncthreads();
    if (t == 0) {
        float lg[NK];
        float m = -1e30f;
        for (int k = 0; k < NK; ++k) {
            float s = 0.f;
            for (int j = 0; j < HID; ++j) s += h[j] * w2[k * HID + j];
            lg[k] = s * (1.0f / TEMP);
            m = fmaxf(m, lg[k]);
        }
        float e[NK], tot = 0.f;
        for (int k = 0; k < NK; ++k) { e[k] = expf(lg[k] - m); tot += e[k]; }
        float inv = 1.0f / tot;
        for (int k = 0; k < NK; ++k) { att[k] = e[k] * inv; att_g[b * NK + k] = att[k]; }
    }
    __syncthreads();
    if (t < CO) {
        float s = 0.f;
        for (int k = 0; k < NK; ++k) s += att[k] * bias[k * CO + t];
        aggb_g[b * CO + t] = s;
    }
}

// load 16-float window xw[j] = x_row[gb + j], zero outside [0, LEN)
template <bool GUARD>
__device__ __forceinline__ void load_xwin(const float* __restrict__ xr, int gb, float* xw) {
    if (!GUARD) {
#pragma unroll
        for (int j = 0; j < 4; ++j) {
            float4 v = *reinterpret_cast<const float4*>(xr + gb + 4 * j);
            xw[4 * j + 0] = v.x; xw[4 * j + 1] = v.y;
            xw[4 * j + 2] = v.z; xw[4 * j + 3] = v.w;
        }
    } else {
#pragma unroll
        for (int j = 0; j < 16; ++j) {
            int c = gb + j;
            xw[j] = (c >= 0 && c < LEN) ? xr[c] : 0.f;
        }
    }
}

template <bool GUARD>
__device__ __forceinline__ void conv_chunk(const float* __restrict__ xb,
                                           const float* __restrict__ wlds,
                                           float* __restrict__ ob,
                                           const float* bb,
                                           int Lb, int lg, int o_loc) {
    int l0 = Lb + lg * LT;
    int gb = l0 - 4;     // window covers x cols gb .. gb+15; need dl+f-3 in [l0-3, l0+10]
    float acc[4][LT];
#pragma unroll
    for (int oo = 0; oo < 4; ++oo)
#pragma unroll
        for (int dl = 0; dl < LT; ++dl) acc[oo][dl] = 0.f;

    float xwn[16];
    load_xwin<GUARD>(xb, gb, xwn);

    for (int i = 0; i < CI; ++i) {
        float xw[16];
#pragma unroll
        for (int j = 0; j < 16; ++j) xw[j] = xwn[j];
        if (i + 1 < CI) load_xwin<GUARD>(xb + (size_t)(i + 1) * LEN, gb, xwn);

        const float* wr = wlds + i * (KS * OTILE);
#pragma unroll
        for (int f = 0; f < KS; ++f) {
            float4 wv = *reinterpret_cast<const float4*>(wr + f * OTILE + o_loc);
#pragma unroll
            for (int dl = 0; dl < LT; ++dl) {
                float xv = xw[dl + f + 1];   // x[l0+dl+f-3] = xw[dl+f-3+4]
                acc[0][dl] = fmaf(wv.x, xv, acc[0][dl]);
                acc[1][dl] = fmaf(wv.y, xv, acc[1][dl]);
                acc[2][dl] = fmaf(wv.z, xv, acc[2][dl]);
                acc[3][dl] = fmaf(wv.w, xv, acc[3][dl]);
            }
        }
    }
#pragma unroll
    for (int oo = 0; oo < 4; ++oo) {
        float4 r0 = make_float4(acc[oo][0] + bb[oo], acc[oo][1] + bb[oo],
                                acc[oo][2] + bb[oo], acc[oo][3] + bb[oo]);
        float4 r1 = make_float4(acc[oo][4] + bb[oo], acc[oo][5] + bb[oo],
                                acc[oo][6] + bb[oo], acc[oo][7] + bb[oo]);
        *reinterpret_cast<float4*>(ob + (size_t)oo * LEN + l0) = r0;
        *reinterpret_cast<float4*>(ob + (size_t)oo * LEN + l0 + 4) = r1;
    }
}

__global__ __launch_bounds__(256, 2) void conv_kernel(
    const float* __restrict__ x,
    const float* __restrict__ weight,
    const float* __restrict__ att_g,
    const float* __restrict__ aggb_g,
    float* __restrict__ out) {
    int blk = blockIdx.x;
    int b = blk >> 3;
    int ot = (blk >> 1) & 3;
    int half = blk & 1;

    __shared__ float wlds[CI * KS * OTILE];   // [i][f][o_local], 14336 floats = 57 KB

    // aggregate the 4 weight banks with att[b][k] into LDS
    float a0 = att_g[b * NK + 0], a1 = att_g[b * NK + 1];
    float a2 = att_g[b * NK + 2], a3 = att_g[b * NK + 3];
    const float* wb = weight + (size_t)ot * OTILE * (CI * KS);
    const int KSTR = CO * CI * KS;            // 57344
    for (int m = threadIdx.x; m < CI * KS * OTILE; m += 256) {
        int o = m & 31;                        // conflict-free LDS writes (m = lds index)
        int g = o * (CI * KS) + (m >> 5);      // [o][i*7+f] in global bank
        wlds[m] = a0 * wb[g] + a1 * wb[g + KSTR] + a2 * wb[g + 2 * KSTR] + a3 * wb[g + 3 * KSTR];
    }

    int tid = threadIdx.x;
    int og = tid >> 5;                         // 8 o-groups of 4 outs
    int lg = tid & 31;                         // 32 l-groups of LT=8
    int o_loc = og * 4;
    int obase = ot * OTILE + o_loc;

    float bb[4];
#pragma unroll
    for (int oo = 0; oo < 4; ++oo) bb[oo] = aggb_g[b * CO + obase + oo];

    const float* xb = x + (size_t)b * CI * LEN;
    float* ob = out + ((size_t)b * CO + obase) * LEN;

    __syncthreads();

    for (int c = 0; c < LHALF / LCHUNK; ++c) {
        int Lb = half * LHALF + c * LCHUNK;
        bool boundary = (Lb == 0) || (Lb == LEN - LCHUNK);
        if (boundary)
            conv_chunk<true>(xb, wlds, ob, bb, Lb, lg, o_loc);
        else
            conv_chunk<false>(xb, wlds, ob, bb, Lb, lg, o_loc);
    }
}

extern "C" void kernel_launch(void* const* d_in, const int* in_sizes, int n_in,
                              void* d_out, int out_size, void* d_ws, size_t ws_size,
                              hipStream_t stream) {
    const float* x  = (const float*)d_in[0];
    const float* w1 = (const float*)d_in[1];
    const float* w2 = (const float*)d_in[2];
    const float* wt = (const float*)d_in[3];
    const float* bs = (const float*)d_in[4];
    float* out = (float*)d_out;
    float* ws = (float*)d_ws;

    float* pooled = ws;                 // BS*CI = 4096 floats
    float* att    = ws + BS * CI;       // BS*NK = 256 floats
    float* aggb   = att + BS * NK;      // BS*CO = 8192 floats

    pool_kernel<<<BS * CI, 256, 0, stream>>>(x, pooled);
    attn_kernel<<<BS, 256, 0, stream>>>(pooled, w1, w2, bs, att, aggb);
    conv_kernel<<<BS * 8, 256, 0, stream>>>(x, wt, att, aggb, out);
}

// Round 2
// 125.017 us; speedup vs baseline: 4.0837x; 4.0837x over previous
//
#include <hip/hip_runtime.h>

typedef __bf16 bf16;
typedef __bf16 bf16x8 __attribute__((ext_vector_type(8)));
typedef float f32x4 __attribute__((ext_vector_type(4)));

#define BS 64
#define CI 64
#define LEN 4096
#define CO 128
#define KS 7
#define NK 4
#define HID 16
#define TEMP 30.0f

#define KTOT 448            // CI*KS
#define WROW 456            // padded W'' row (elems); 912B, 16B-aligned, bank-uniform
#define WBAT (CO * WROW)    // 58368 elems per batch
#define XROW 72             // padded x-tile row (i dim); 144B
#define XC 134              // c rows (l-window 128 + 6 halo)
#define LTILE 128
#define TPB 4               // L-tiles per block
#define LSPL 8              // l-splits per batch

// ---------------- pool: mean over L ----------------
__global__ void pool_kernel(const float* __restrict__ x, float* __restrict__ pooled) {
    int bc = blockIdx.x;
    const float4* xp = (const float4*)(x + (size_t)bc * LEN);
    int t = threadIdx.x;
    float s = 0.f;
#pragma unroll
    for (int j = 0; j < 4; ++j) {
        float4 v = xp[t + 256 * j];
        s += (v.x + v.y) + (v.z + v.w);
    }
#pragma unroll
    for (int off = 32; off > 0; off >>= 1) s += __shfl_down(s, off, 64);
    __shared__ float red[4];
    if ((t & 63) == 0) red[t >> 6] = s;
    __syncthreads();
    if (t == 0) pooled[bc] = (red[0] + red[1] + red[2] + red[3]) * (1.0f / LEN);
}

// ---------------- attention ----------------
__global__ void attn_kernel(const float* __restrict__ pooled,
                            const float* __restrict__ w1,
                            const float* __restrict__ w2,
                            const float* __restrict__ bias,
                            float* __restrict__ att_g,
                            float* __restrict__ aggb_g) {
    int b = blockIdx.x, t = threadIdx.x;
    __shared__ float p[CI], h[HID], att[NK];
    if (t < CI) p[t] = pooled[b * CI + t];
    __syncthreads();
    if (t < HID) {
        float s = 0.f;
        for (int i = 0; i < CI; ++i) s += p[i] * w1[t * CI + i];
        h[t] = fmaxf(s, 0.f);
    }
    __syncthreads();
    if (t == 0) {
        float lg[NK];
        float m = -1e30f;
        for (int k = 0; k < NK; ++k) {
            float s = 0.f;
            for (int j = 0; j < HID; ++j) s += h[j] * w2[k * HID + j];
            lg[k] = s * (1.0f / TEMP);
            m = fmaxf(m, lg[k]);
        }
        float e[NK], tot = 0.f;
        for (int k = 0; k < NK; ++k) { e[k] = expf(lg[k] - m); tot += e[k]; }
        float inv = 1.0f / tot;
        for (int k = 0; k < NK; ++k) { att[k] = e[k] * inv; att_g[b * NK + k] = att[k]; }
    }
    __syncthreads();
    if (t < CO) {
        float s = 0.f;
        for (int k = 0; k < NK; ++k) s += att[k] * bias[k * CO + t];
        aggb_g[b * CO + t] = s;
    }
}

// ---------------- aggregate weight banks -> bf16, MFMA-ready layout ----------------
// wagg[b][o][k] with k = f*64 + i, row padded to WROW
__global__ void aggw_kernel(const float* __restrict__ weight,
                            const float* __restrict__ att_g,
                            bf16* __restrict__ wagg) {
    int b = blockIdx.x, t = threadIdx.x;
    float a0 = att_g[b * NK + 0], a1 = att_g[b * NK + 1];
    float a2 = att_g[b * NK + 2], a3 = att_g[b * NK + 3];
    bf16* wb = wagg + (size_t)b * WBAT;
    const int KSTR = CO * CI * KS;   // 57344
    for (int m = t; m < KSTR; m += 256) {
        int o = m / KTOT;
        int r = m - o * KTOT;
        int i = r / KS;
        int f = r - i * KS;
        float v = a0 * weight[m] + a1 * weight[m + KSTR] +
                  a2 * weight[m + 2 * KSTR] + a3 * weight[m + 3 * KSTR];
        wb[o * WROW + f * 64 + i] = (bf16)v;
    }
}

// ---------------- conv: implicit GEMM on MFMA ----------------
struct XStage { float4 m[8]; float e1, e2; };

__global__ __launch_bounds__(256, 1) void conv_kernel(
    const float* __restrict__ x,
    const bf16* __restrict__ wagg,
    const float* __restrict__ aggb,
    float* __restrict__ out) {
    __shared__ __align__(16) bf16 lds_w[CO * WROW];      // 116736 B
    __shared__ __align__(16) bf16 lds_x[2][XC * XROW];   // 2 x 19296 B

    int blk = blockIdx.x;
    int b = blk >> 3, lsp = blk & 7;
    int t = threadIdx.x;
    int lane = t & 63, wid = t >> 6;
    int ln = lane & 15, g = lane >> 4;
    int wm = wid >> 1, wn = wid & 1;

    // ---- stage W_b (linear copy, 16B chunks) ----
    {
        const int4* src = (const int4*)(wagg + (size_t)b * WBAT);
        int4* dst = (int4*)lds_w;
        for (int c = t; c < WBAT / 8; c += 256) dst[c] = src[c];
    }

    // bias + output row offsets (o = wm*64 + mf*16 + g*4 + r)
    float bias_r[4][4];
    int orow_off[4][4];
#pragma unroll
    for (int mf = 0; mf < 4; ++mf)
#pragma unroll
        for (int r = 0; r < 4; ++r) {
            int o = wm * 64 + mf * 16 + g * 4 + r;
            bias_r[mf][r] = aggb[b * CO + o];
            orow_off[mf][r] = (b * CO + o) * LEN;
        }

    const bf16* apb[4];
#pragma unroll
    for (int mf = 0; mf < 4; ++mf)
        apb[mf] = lds_w + (wm * 64 + mf * 16 + ln) * WROW + g * 8;

    int l0base = lsp * (LTILE * TPB);
    int si = t >> 2, sf = t & 3;
    const float* xb = x + (size_t)b * CI * LEN;

    auto load_x = [&](int l0, XStage& s) {
#pragma unroll
        for (int j = 0; j < 8; ++j) {
            int c4 = sf + 4 * j;
            s.m[j] = *(const float4*)(xb + (size_t)si * LEN + l0 + 4 * c4);
        }
        int i1 = t / 6, s1 = t - i1 * 6;
        int c1 = (s1 < 3) ? s1 : (128 + s1);
        int gl1 = l0 - 3 + c1;
        s.e1 = (gl1 >= 0 && gl1 < LEN) ? xb[(size_t)i1 * LEN + gl1] : 0.f;
        s.e2 = 0.f;
        if (t < 128) {
            int e2 = 256 + t, i2 = e2 / 6, s2 = e2 - i2 * 6;
            int c2 = (s2 < 3) ? s2 : (128 + s2);
            int gl2 = l0 - 3 + c2;
            s.e2 = (gl2 >= 0 && gl2 < LEN) ? xb[(size_t)i2 * LEN + gl2] : 0.f;
        }
    };
    auto write_x = [&](int buf, const XStage& s) {
        bf16* lb = lds_x[buf];
#pragma unroll
        for (int j = 0; j < 8; ++j) {
            int c4 = sf + 4 * j;
#pragma unroll
            for (int dl = 0; dl < 4; ++dl) {
                float v = (&s.m[j].x)[dl];
                lb[(4 * c4 + 3 + dl) * XROW + si] = (bf16)v;
            }
        }
        int i1 = t / 6, s1 = t - i1 * 6;
        int c1 = (s1 < 3) ? s1 : (128 + s1);
        lb[c1 * XROW + i1] = (bf16)s.e1;
        if (t < 128) {
            int e2 = 256 + t, i2 = e2 / 6, s2 = e2 - i2 * 6;
            int c2 = (s2 < 3) ? s2 : (128 + s2);
            lb[c2 * XROW + i2] = (bf16)s.e2;
        }
    };

    XStage s0;
    load_x(l0base, s0);
    write_x(0, s0);
    __syncthreads();

    for (int tl = 0; tl < TPB; ++tl) {
        int l0 = l0base + tl * LTILE;
        XStage sn;
        if (tl + 1 < TPB) load_x(l0 + LTILE, sn);   // issue early (T14)

        f32x4 acc[4][4];
#pragma unroll
        for (int mf = 0; mf < 4; ++mf)
#pragma unroll
            for (int nf = 0; nf < 4; ++nf)
                acc[mf][nf] = (f32x4){0.f, 0.f, 0.f, 0.f};

        const bf16* bpb[4];
#pragma unroll
        for (int nf = 0; nf < 4; ++nf)
            bpb[nf] = lds_x[tl & 1] + (wn * 64 + nf * 16 + ln) * XROW + g * 8;

#pragma unroll
        for (int kk = 0; kk < 14; ++kk) {
            int aoff = kk * 32;                          // k = f*64+i, 32 per step
            int boff = (kk >> 1) * XROW + (kk & 1) * 32; // row shift f, col shift i
            bf16x8 av[4], bv[4];
#pragma unroll
            for (int mf = 0; mf < 4; ++mf)
                av[mf] = *(const bf16x8*)(apb[mf] + aoff);
#pragma unroll
            for (int nf = 0; nf < 4; ++nf)
                bv[nf] = *(const bf16x8*)(bpb[nf] + boff);
#pragma unroll
            for (int mf = 0; mf < 4; ++mf)
#pragma unroll
                for (int nf = 0; nf < 4; ++nf)
                    acc[mf][nf] = __builtin_amdgcn_mfma_f32_16x16x32_bf16(
                        av[mf], bv[nf], acc[mf][nf], 0, 0, 0);
        }

        // store + bias
#pragma unroll
        for (int mf = 0; mf < 4; ++mf)
#pragma unroll
            for (int nf = 0; nf < 4; ++nf) {
                int l = l0 + wn * 64 + nf * 16 + ln;
#pragma unroll
                for (int r = 0; r < 4; ++r)
                    out[(size_t)orow_off[mf][r] + l] = acc[mf][nf][r] + bias_r[mf][r];
            }

        if (tl + 1 < TPB) write_x((tl + 1) & 1, sn);   // other buffer: safe post-barrier
        __syncthreads();
    }
}

extern "C" void kernel_launch(void* const* d_in, const int* in_sizes, int n_in,
                              void* d_out, int out_size, void* d_ws, size_t ws_size,
                              hipStream_t stream) {
    const float* x  = (const float*)d_in[0];
    const float* w1 = (const float*)d_in[1];
    const float* w2 = (const float*)d_in[2];
    const float* wt = (const float*)d_in[3];
    const float* bs = (const float*)d_in[4];
    float* out = (float*)d_out;

    bf16* wagg = (bf16*)d_ws;                                  // 64*58368*2 = 7,471,104 B
    float* pooled = (float*)((char*)d_ws + (size_t)BS * WBAT * 2);
    float* att    = pooled + BS * CI;
    float* aggb   = att + BS * NK;

    pool_kernel<<<BS * CI, 256, 0, stream>>>(x, pooled);
    attn_kernel<<<BS, 256, 0, stream>>>(pooled, w1, w2, bs, att, aggb);
    aggw_kernel<<<BS, 256, 0, stream>>>(wt, att, wagg);
    conv_kernel<<<BS * LSPL, 256, 0, stream>>>(x, wagg, aggb, out);
}

// Round 3
// 113.936 us; speedup vs baseline: 4.4809x; 1.0973x over previous
//
#include <hip/hip_runtime.h>

typedef __bf16 bf16;
typedef __bf16 bf16x8 __attribute__((ext_vector_type(8)));
typedef float f32x4 __attribute__((ext_vector_type(4)));

#define BS 64
#define CI 64
#define LEN 4096
#define CO 128
#define KS 7
#define NK 4
#define HID 16
#define TEMP 30.0f

#define KTOT 448            // CI*KS
#define WROW 456            // padded W row (elems); 912B, 16B-aligned, bank-uniform
#define WBAT (CO * WROW)    // 58368 elems per batch
#define XROW 72             // padded x-tile row (i dim); 144B
#define XC 134              // l-window 128 + 6 halo
#define LTILE 128
#define TPB 4               // L-tiles per block
#define LSPL 8              // l-splits per batch

// ---------------- pool: mean over L ----------------
__global__ void pool_kernel(const float* __restrict__ x, float* __restrict__ pooled) {
    int bc = blockIdx.x;
    const float4* xp = (const float4*)(x + (size_t)bc * LEN);
    int t = threadIdx.x;
    float s = 0.f;
#pragma unroll
    for (int j = 0; j < 4; ++j) {
        float4 v = xp[t + 256 * j];
        s += (v.x + v.y) + (v.z + v.w);
    }
#pragma unroll
    for (int off = 32; off > 0; off >>= 1) s += __shfl_down(s, off, 64);
    __shared__ float red[4];
    if ((t & 63) == 0) red[t >> 6] = s;
    __syncthreads();
    if (t == 0) pooled[bc] = (red[0] + red[1] + red[2] + red[3]) * (1.0f / LEN);
}

// ---------------- attention + weight aggregation (fused) ----------------
__global__ void attn_aggw_kernel(const float* __restrict__ pooled,
                                 const float* __restrict__ w1,
                                 const float* __restrict__ w2,
                                 const float* __restrict__ bias,
                                 const float* __restrict__ weight,
                                 float* __restrict__ aggb_g,
                                 bf16* __restrict__ wagg) {
    int b = blockIdx.x, t = threadIdx.x;
    __shared__ float p[CI], h[HID], att[NK];
    if (t < CI) p[t] = pooled[b * CI + t];
    __syncthreads();
    if (t < HID) {
        float s = 0.f;
        for (int i = 0; i < CI; ++i) s += p[i] * w1[t * CI + i];
        h[t] = fmaxf(s, 0.f);
    }
    __syncthreads();
    if (t == 0) {
        float lg[NK];
        float m = -1e30f;
        for (int k = 0; k < NK; ++k) {
            float s = 0.f;
            for (int j = 0; j < HID; ++j) s += h[j] * w2[k * HID + j];
            lg[k] = s * (1.0f / TEMP);
            m = fmaxf(m, lg[k]);
        }
        float e[NK], tot = 0.f;
        for (int k = 0; k < NK; ++k) { e[k] = expf(lg[k] - m); tot += e[k]; }
        float inv = 1.0f / tot;
        for (int k = 0; k < NK; ++k) att[k] = e[k] * inv;
    }
    __syncthreads();
    if (t < CO) {
        float s = 0.f;
        for (int k = 0; k < NK; ++k) s += att[k] * bias[k * CO + t];
        aggb_g[b * CO + t] = s;
    }
    float a0 = att[0], a1 = att[1], a2 = att[2], a3 = att[3];
    bf16* wb = wagg + (size_t)b * WBAT;
    const int KSTR = CO * CI * KS;   // 57344
    for (int m = t; m < KSTR; m += 256) {
        int o = m / KTOT;
        int r = m - o * KTOT;
        int i = r / KS;
        int f = r - i * KS;
        float v = a0 * weight[m] + a1 * weight[m + KSTR] +
                  a2 * weight[m + 2 * KSTR] + a3 * weight[m + 3 * KSTR];
        wb[o * WROW + f * 64 + i] = (bf16)v;
    }
}

// ---------------- conv: implicit GEMM on MFMA, 2 blocks/CU ----------------
struct XStage { float4 m[8]; float e1, e2; };

__global__ __launch_bounds__(256, 2) void conv_kernel(
    const float* __restrict__ x,
    const bf16* __restrict__ wagg,
    const float* __restrict__ aggb,
    float* __restrict__ out) {
    __shared__ __align__(16) bf16 lds_w[64 * WROW];    // 58368 B
    __shared__ __align__(16) bf16 lds_x[XC * XROW];    // 19296 B  (total 77664 B -> 2 blocks/CU)

    int nwg = gridDim.x;                               // 1024 (multiple of 8: bijective)
    int bid = blockIdx.x;
    int logical = (bid & 7) * (nwg >> 3) + (bid >> 3); // XCD-chunked swizzle (T1)
    int b = logical >> 4;
    int rem = logical & 15;
    int oh = rem >> 3, lsp = rem & 7;

    int t = threadIdx.x;
    int lane = t & 63, wid = t >> 6;
    int ln = lane & 15, g = lane >> 4;
    int wm = wid >> 1, wn = wid & 1;                   // wave tile: 32 o x 64 l

    // ---- stage this o-half of W_b (linear 16B copy) ----
    {
        const int4* src = (const int4*)(wagg + (size_t)b * WBAT + (size_t)oh * 64 * WROW);
        int4* dst = (int4*)lds_w;
        for (int c = t; c < 64 * WROW / 8; c += 256) dst[c] = src[c];
    }

    // bias + output row offsets: o = oh*64 + wm*32 + mf*16 + g*4 + r
    float bias_r[2][4];
    int orow_off[2][4];
#pragma unroll
    for (int mf = 0; mf < 2; ++mf)
#pragma unroll
        for (int r = 0; r < 4; ++r) {
            int o = oh * 64 + wm * 32 + mf * 16 + g * 4 + r;
            bias_r[mf][r] = aggb[b * CO + o];
            orow_off[mf][r] = (b * CO + o) * LEN;
        }

    const bf16* apb[2];
#pragma unroll
    for (int mf = 0; mf < 2; ++mf)
        apb[mf] = lds_w + (wm * 32 + mf * 16 + ln) * WROW + g * 8;

    int l0base = lsp * (LTILE * TPB);
    int si = t >> 2, sf = t & 3;
    const float* xb = x + (size_t)b * CI * LEN;

    auto load_x = [&](int l0, XStage& s) {
#pragma unroll
        for (int j = 0; j < 8; ++j) {
            int c4 = sf + 4 * j;
            s.m[j] = *(const float4*)(xb + (size_t)si * LEN + l0 + 4 * c4);
        }
        int i1 = t / 6, s1 = t - i1 * 6;
        int c1 = (s1 < 3) ? s1 : (128 + s1);
        int gl1 = l0 - 3 + c1;
        s.e1 = (gl1 >= 0 && gl1 < LEN) ? xb[(size_t)i1 * LEN + gl1] : 0.f;
        s.e2 = 0.f;
        if (t < 128) {
            int e2 = 256 + t, i2 = e2 / 6, s2 = e2 - i2 * 6;
            int c2 = (s2 < 3) ? s2 : (128 + s2);
            int gl2 = l0 - 3 + c2;
            s.e2 = (gl2 >= 0 && gl2 < LEN) ? xb[(size_t)i2 * LEN + gl2] : 0.f;
        }
    };
    auto write_x = [&](const XStage& s) {
#pragma unroll
        for (int j = 0; j < 8; ++j) {
            int c4 = sf + 4 * j;
#pragma unroll
            for (int dl = 0; dl < 4; ++dl) {
                float v = (&s.m[j].x)[dl];
                lds_x[(4 * c4 + 3 + dl) * XROW + si] = (bf16)v;
            }
        }
        int i1 = t / 6, s1 = t - i1 * 6;
        int c1 = (s1 < 3) ? s1 : (128 + s1);
        lds_x[c1 * XROW + i1] = (bf16)s.e1;
        if (t < 128) {
            int e2 = 256 + t, i2 = e2 / 6, s2 = e2 - i2 * 6;
            int c2 = (s2 < 3) ? s2 : (128 + s2);
            lds_x[c2 * XROW + i2] = (bf16)s.e2;
        }
    };

    XStage s0;
    load_x(l0base, s0);
    write_x(s0);
    __syncthreads();

    for (int tl = 0; tl < TPB; ++tl) {
        int l0 = l0base + tl * LTILE;
        XStage sn;
        if (tl + 1 < TPB) load_x(l0 + LTILE, sn);   // issue early (T14)

        f32x4 acc[2][4];
#pragma unroll
        for (int mf = 0; mf < 2; ++mf)
#pragma unroll
            for (int nf = 0; nf < 4; ++nf)
                acc[mf][nf] = (f32x4){0.f, 0.f, 0.f, 0.f};

        const bf16* bpb[4];
#pragma unroll
        for (int nf = 0; nf < 4; ++nf)
            bpb[nf] = lds_x + (wn * 64 + nf * 16 + ln) * XROW + g * 8;

#pragma unroll
        for (int kk = 0; kk < 14; ++kk) {
            int aoff = kk * 32;                          // k = f*64+i
            int boff = (kk >> 1) * XROW + (kk & 1) * 32; // row shift f, col shift i-half
            bf16x8 av[2], bv[4];
#pragma unroll
            for (int mf = 0; mf < 2; ++mf)
                av[mf] = *(const bf16x8*)(apb[mf] + aoff);
#pragma unroll
            for (int nf = 0; nf < 4; ++nf)
                bv[nf] = *(const bf16x8*)(bpb[nf] + boff);
#pragma unroll
            for (int mf = 0; mf < 2; ++mf)
#pragma unroll
                for (int nf = 0; nf < 4; ++nf)
                    acc[mf][nf] = __builtin_amdgcn_mfma_f32_16x16x32_bf16(
                        av[mf], bv[nf], acc[mf][nf], 0, 0, 0);
        }

        // store + bias
#pragma unroll
        for (int mf = 0; mf < 2; ++mf)
#pragma unroll
            for (int nf = 0; nf < 4; ++nf) {
                int l = l0 + wn * 64 + nf * 16 + ln;
#pragma unroll
                for (int r = 0; r < 4; ++r)
                    out[(size_t)orow_off[mf][r] + l] = acc[mf][nf][r] + bias_r[mf][r];
            }

        __syncthreads();                 // all waves done reading lds_x
        if (tl + 1 < TPB) {
            write_x(sn);
            __syncthreads();             // new tile visible
        }
    }
}

extern "C" void kernel_launch(void* const* d_in, const int* in_sizes, int n_in,
                              void* d_out, int out_size, void* d_ws, size_t ws_size,
                              hipStream_t stream) {
    const float* x  = (const float*)d_in[0];
    const float* w1 = (const float*)d_in[1];
    const float* w2 = (const float*)d_in[2];
    const float* wt = (const float*)d_in[3];
    const float* bs = (const float*)d_in[4];
    float* out = (float*)d_out;

    bf16* wagg = (bf16*)d_ws;                                  // 64*58368*2 B
    float* pooled = (float*)((char*)d_ws + (size_t)BS * WBAT * 2);
    float* aggb   = pooled + BS * CI;

    pool_kernel<<<BS * CI, 256, 0, stream>>>(x, pooled);
    attn_aggw_kernel<<<BS, 256, 0, stream>>>(pooled, w1, w2, bs, wt, aggb, wagg);
    conv_kernel<<<BS * 16, 256, 0, stream>>>(x, wagg, aggb, out);
}